// Round 12
// baseline (1138.327 us; speedup 1.0000x reference)
//
#include <hip/hip_runtime.h>
#include <math.h>

#define BB 4
#define NN 2048              // N == M
#define TPB 512
#define WVS 8                // waves per block = rows per block (1 row/wave)
#define BPB (NN/WVS)         // 256 blocks (strips) per batch
#define NBLK (BB*BPB)        // 1024 blocks
#define SLOT (BB*NN)         // 8192
#define CPL 32               // columns per lane (64 lanes * 32 = 2048)
#define POFF (4*SLOT)        // P[b][strip][m] partials
#define PSZ  (BB*BPB*NN)     // 2M floats (8 MB)
#define COFF (POFF + PSZ)    // costw [NBLK*WVS]

#if __has_builtin(__builtin_amdgcn_exp2f)
  #define FEXP2(x) __builtin_amdgcn_exp2f(x)
#else
  #define FEXP2(x) exp2f(x)
#endif
#if __has_builtin(__builtin_amdgcn_sqrtf)
  #define FSQRT(x) __builtin_amdgcn_sqrtf(x)
#else
  #define FSQRT(x) sqrtf(x)
#endif

// ws float layout:
// [0]       ratL [SLOT]
// [SLOT]    remL [SLOT]
// [2*SLOT]  ratR [SLOT]
// [3*SLOT]  remR [SLOT]
// [POFF]    P    [BB][BPB][NN]
// [COFF]    costw[NBLK*WVS]

__device__ __forceinline__ float wsum(float v) {
#pragma unroll
    for (int off = 32; off > 0; off >>= 1) v += __shfl_xor(v, off, 64);
    return v;   // full sum in ALL lanes (xor butterfly)
}

// K0: suml_0 (weights 1) -> ratL(0); emit P(0)[strip][m] = sum_rows e0*ratL0.
__global__ void __launch_bounds__(TPB)
k_K0(const float* __restrict__ tpl, const float* __restrict__ src,
     float* __restrict__ ws, float lvl) {
    __shared__ float4 pts[NN];     // src {x,y,z,-}
    __shared__ float Pl[NN];
    int bid = blockIdx.x, tid = threadIdx.x;
    int b = bid / BPB, rc = bid % BPB;
    int wv = tid >> 6, lane = tid & 63;
    int gbase = b*NN, g = gbase + rc*WVS + wv;
    for (int i = tid; i < NN; i += TPB) {
        const float* sp = src + (gbase + i)*3;
        pts[i] = make_float4(sp[0], sp[1], sp[2], 0.f);
        Pl[i] = 0.f;
    }
    __syncthreads();
    const float* tp = tpl + g*3;
    float px = tp[0], py = tp[1], pz = tp[2];
    float eA[CPL];
    float a0 = 0.f, a1 = 0.f;
#pragma unroll
    for (int i = 0; i < CPL; ++i) {
        float4 s = pts[lane + (i << 6)];
        float dx = px-s.x, dy = py-s.y, dz = pz-s.z;
        float e = FEXP2(lvl*(dx*dx + dy*dy + dz*dz));
        eA[i] = e;
        if (i & 1) a1 += e; else a0 += e;
    }
    float a = wsum(a0 + a1);
    float ratL0 = 1.0f / (a + 1e-9f);
    if (lane == 0) {
        ws[g] = ratL0;
        ws[COFF + bid*WVS + wv] = 0.f;
    }
#pragma unroll
    for (int i = 0; i < CPL; ++i)
        atomicAdd(&Pl[lane + (i << 6)], eA[i] * ratL0);
    __syncthreads();
    float* P = ws + POFF + (size_t)(b*BPB + rc)*NN;
    for (int i = tid; i < NN; i += TPB) P[i] = Pl[i];
}

// Y(k): sumr[m] = sum_strips P -> ratR, remR update. 32 blocks x 256.
__global__ void k_Y(float* __restrict__ ws, int first) {
    int gm = blockIdx.x*256 + threadIdx.x;    // [0, SLOT)
    int b = gm >> 11, m = gm & (NN - 1);
    const float* P = ws + POFF + (size_t)(b*BPB)*NN + m;
    float s = 0.f;
#pragma unroll 8
    for (int st = 0; st < BPB; ++st) s += P[(size_t)st*NN];
    float* ratR = ws + 2*SLOT;
    float* remR = ws + 3*SLOT;
    float rr = first ? 1.0f : remR[gm];
    float rt = rr / (s + 1e-9f);
    ratR[gm] = rt;
    remR[gm] = fmaxf(rr - rt*s, 0.0f);        // colsum = ratioR*sumr (exact)
}

// CA(k), k=0..7: C(k) {eC = eA^4, rowsum->remL, cost} + A(k+1) {eA -> ratL(k+1)}
// + emit P(k+1) from the SAME in-register eA values.
__global__ void __launch_bounds__(TPB)
k_CA(const float* __restrict__ tpl, const float* __restrict__ src,
     float* __restrict__ ws, float lvlA, int first) {
    __shared__ float4 pts[NN];     // {x,y,z, ratR(k)}
    __shared__ float wM[NN];       // remR (post-k)
    __shared__ float Pl[NN];
    int bid = blockIdx.x, tid = threadIdx.x;
    int b = bid / BPB, rc = bid % BPB;
    int wv = tid >> 6, lane = tid & 63;
    int gbase = b*NN, g = gbase + rc*WVS + wv;
    const float* ratR = ws + 2*SLOT;
    const float* remR = ws + 3*SLOT;
    for (int i = tid; i < NN; i += TPB) {
        const float* sp = src + (gbase + i)*3;
        pts[i] = make_float4(sp[0], sp[1], sp[2], ratR[gbase + i]);
        wM[i] = remR[gbase + i];
        Pl[i] = 0.f;
    }
    __syncthreads();
    const float* tp = tpl + g*3;
    float px = tp[0], py = tp[1], pz = tp[2];
    float eA[CPL];
    float r0 = 0.f, r1 = 0.f, c0 = 0.f, c1 = 0.f, a0 = 0.f, a1 = 0.f;
#pragma unroll
    for (int i = 0; i < CPL; ++i) {
        int m = lane + (i << 6);
        float4 s = pts[m];
        float dx = px-s.x, dy = py-s.y, dz = pz-s.z;
        float d2 = dx*dx + dy*dy + dz*dz;
        float e = FEXP2(lvlA*d2);
        eA[i] = e;
        float sq = e*e;
        float t = (sq*sq) * s.w;              // exp2(lvlC*d2)*ratR, lvlC=4*lvlA
        float ds = FSQRT(fmaxf(d2, 1e-24f));
        if (i & 1) { r1 += t; c1 += t*ds; a1 += e*wM[m]; }
        else       { r0 += t; c0 += t*ds; a0 += e*wM[m]; }
    }
    float r = wsum(r0 + r1), c = wsum(c0 + c1), a = wsum(a0 + a1);
    float rlRat = ws[g];                      // ratL at level k (broadcast load)
    float rl = first ? 1.0f : ws[SLOT + g];   // remL
    float rlnew = fmaxf(rl - rlRat*r, 0.0f);
    float ratLn = rlnew / (a + 1e-9f);        // ratL at level k+1
    if (lane == 0) {
        ws[SLOT + g] = rlnew;
        ws[g] = ratLn;
        ws[COFF + bid*WVS + wv] += rlRat * c;
    }
#pragma unroll
    for (int i = 0; i < CPL; ++i)
        atomicAdd(&Pl[lane + (i << 6)], eA[i] * ratLn);
    __syncthreads();
    float* P = ws + POFF + (size_t)(b*BPB + rc)*NN;
    for (int i = tid; i < NN; i += TPB) P[i] = Pl[i];
}

// CA8: C(8) {direct e8} + A(9) {lvl=0 -> suml = sum(remR) = Rtot}. No P emit.
__global__ void __launch_bounds__(TPB)
k_CA8(const float* __restrict__ tpl, const float* __restrict__ src,
      float* __restrict__ ws, float lvlC) {
    __shared__ float4 pts[NN];     // {x,y,z, ratR(8)}
    __shared__ float wM[NN];       // remR (post-8)
    __shared__ float srt[WVS];
    int bid = blockIdx.x, tid = threadIdx.x;
    int b = bid / BPB, rc = bid % BPB;
    int wv = tid >> 6, lane = tid & 63;
    int gbase = b*NN, g = gbase + rc*WVS + wv;
    const float* ratR = ws + 2*SLOT;
    const float* remR = ws + 3*SLOT;
    float part = 0.f;
    for (int i = tid; i < NN; i += TPB) {
        const float* sp = src + (gbase + i)*3;
        float v = remR[gbase + i];
        pts[i] = make_float4(sp[0], sp[1], sp[2], ratR[gbase + i]);
        wM[i] = v;
        part += v;
    }
    part = wsum(part);
    if (lane == 0) srt[wv] = part;
    __syncthreads();
    float Rtot = 0.f;
#pragma unroll
    for (int w = 0; w < WVS; ++w) Rtot += srt[w];
    const float* tp = tpl + g*3;
    float px = tp[0], py = tp[1], pz = tp[2];
    float r0 = 0.f, r1 = 0.f, c0 = 0.f, c1 = 0.f;
#pragma unroll
    for (int i = 0; i < CPL; ++i) {
        float4 s = pts[lane + (i << 6)];
        float dx = px-s.x, dy = py-s.y, dz = pz-s.z;
        float d2 = dx*dx + dy*dy + dz*dz;
        float t = FEXP2(lvlC*d2) * s.w;
        float ds = FSQRT(fmaxf(d2, 1e-24f));
        if (i & 1) { r1 += t; c1 += t*ds; }
        else       { r0 += t; c0 += t*ds; }
    }
    float r = wsum(r0 + r1), c = wsum(c0 + c1);
    float rlRat = ws[g];
    float rlnew = fmaxf(ws[SLOT + g] - rlRat*r, 0.0f);
    if (lane == 0) {
        ws[g] = rlnew / (Rtot + 1e-9f);       // ratL at level 9
        ws[COFF + bid*WVS + wv] += rlRat * c;
    }
}

// C9 (level 9, lvl=0): sumr9 = sum(ratL9) = Stot; cost += ratL9[n]/Stot * sum_m remR[m]*d.
__global__ void __launch_bounds__(TPB)
k_C9(const float* __restrict__ tpl, const float* __restrict__ src,
     float* __restrict__ ws) {
    __shared__ float4 pts[NN];     // {x,y,z, remR}
    __shared__ float srt[WVS];
    int bid = blockIdx.x, tid = threadIdx.x;
    int b = bid / BPB, rc = bid % BPB;
    int wv = tid >> 6, lane = tid & 63;
    int gbase = b*NN, g = gbase + rc*WVS + wv;
    const float* remR = ws + 3*SLOT;
    float part = 0.f;
    for (int i = tid; i < NN; i += TPB) {
        const float* sp = src + (gbase + i)*3;
        pts[i] = make_float4(sp[0], sp[1], sp[2], remR[gbase + i]);
        part += ws[gbase + i];                // ratL9
    }
    part = wsum(part);
    if (lane == 0) srt[wv] = part;
    __syncthreads();
    float Stot = 0.f;
#pragma unroll
    for (int w = 0; w < WVS; ++w) Stot += srt[w];
    const float* tp = tpl + g*3;
    float px = tp[0], py = tp[1], pz = tp[2];
    float c0 = 0.f, c1 = 0.f;
#pragma unroll
    for (int i = 0; i < CPL; ++i) {
        float4 s = pts[lane + (i << 6)];
        float dx = px-s.x, dy = py-s.y, dz = pz-s.z;
        float d2 = dx*dx + dy*dy + dz*dz;
        float ds = FSQRT(fmaxf(d2, 1e-24f));
        if (i & 1) c1 += s.w * ds; else c0 += s.w * ds;
    }
    float c = wsum(c0 + c1);
    if (lane == 0)
        ws[COFF + bid*WVS + wv] += ws[g] * c / (Stot + 1e-9f);
}

// Final: reduce NBLK*WVS per-wave partials, scale.
__global__ void k_final(const float* __restrict__ ws, float* __restrict__ out) {
    __shared__ float swv[4];
    const float* costw = ws + COFF;
    int tid = threadIdx.x;
    float t = 0.f;
    for (int i = tid; i < NBLK*WVS; i += 256) t += costw[i];
#pragma unroll
    for (int off = 32; off > 0; off >>= 1) t += __shfl_down(t, off, 64);
    if ((tid & 63) == 0) swv[tid >> 6] = t;
    __syncthreads();
    if (tid == 0) out[0] = (swv[0] + swv[1] + swv[2] + swv[3]) * (1.0f / (float)(BB * NN));
}

extern "C" void kernel_launch(void* const* d_in, const int* in_sizes, int n_in,
                              void* d_out, int out_size, void* d_ws, size_t ws_size,
                              hipStream_t stream) {
    const float* tpl = (const float*)d_in[0];
    const float* src = (const float*)d_in[1];
    float* ws = (float*)d_ws;
    float* out = (float*)d_out;

    // lvl2[k] = level_k * log2(e); levels = -4^(7-k) for k=0..8, 0 for k=9
    const double L2E = 1.4426950408889634;
    float lvl2[10];
    for (int k = 0; k < 9; ++k) lvl2[k] = (float)(-pow(4.0, 7 - k) * L2E);
    lvl2[9] = 0.0f;

    k_K0<<<NBLK, TPB, 0, stream>>>(tpl, src, ws, lvl2[0]);
    k_Y <<<SLOT/256, 256, 0, stream>>>(ws, 1);
    for (int k = 0; k < 8; ++k) {
        k_CA<<<NBLK, TPB, 0, stream>>>(tpl, src, ws, lvl2[k+1], k == 0 ? 1 : 0);
        k_Y <<<SLOT/256, 256, 0, stream>>>(ws, 0);
    }
    k_CA8<<<NBLK, TPB, 0, stream>>>(tpl, src, ws, lvl2[8]);
    k_C9 <<<NBLK, TPB, 0, stream>>>(tpl, src, ws);
    k_final<<<1, 256, 0, stream>>>(ws, out);
}